// Round 11
// baseline (694.359 us; speedup 1.0000x reference)
//
#include <hip/hip_runtime.h>
#include <cmath>

#define NPTS 4096
#define NB   8192      // B*N
#define DM   256
#define KK   48

// ---------------------------------------------------------------------------
// C1: Wk2 = Wk@Wpe2, Wv2 = Wv@Wpe2 (256x128 each); bkf = bk + Wk@bpe2, bvf likewise
__global__ __launch_bounds__(128) void prep_wkv2(
    const float* __restrict__ Win, const float* __restrict__ Wpe2,
    const float* __restrict__ bpe2, const float* __restrict__ bin_,
    float* __restrict__ Wk2, float* __restrict__ Wv2,
    float* __restrict__ bkf, float* __restrict__ bvf)
{
    const int o = blockIdx.x;          // 0..255 output row
    const int j = threadIdx.x;         // 0..127
    const float* wk = Win + (size_t)(256 + o) * 256;
    const float* wv = Win + (size_t)(512 + o) * 256;
    float ak = 0.f, av = 0.f;
    for (int d = 0; d < 256; ++d) {
        float pw = Wpe2[(size_t)d * 128 + j];
        ak = fmaf(wk[d], pw, ak);
        av = fmaf(wv[d], pw, av);
    }
    Wk2[(size_t)o * 128 + j] = ak;
    Wv2[(size_t)o * 128 + j] = av;

    __shared__ float pk[128], pv[128];
    pk[j] = wk[j] * bpe2[j] + wk[j + 128] * bpe2[j + 128];
    pv[j] = wv[j] * bpe2[j] + wv[j + 128] * bpe2[j + 128];
    __syncthreads();
    for (int off = 64; off >= 1; off >>= 1) {
        if (j < off) { pk[j] += pk[j + off]; pv[j] += pv[j + off]; }
        __syncthreads();
    }
    if (j == 0) {
        bkf[o] = bin_[256 + o] + pk[0];
        bvf[o] = bin_[512 + o] + pv[0];
    }
}

// ---------------------------------------------------------------------------
// C1b: WqW2[o=h*128+j][d] = 0.125 * sum_{d'<64} Win[64h+d'][d] * Wk2[64h+d'][j]
//      bqW2[o]            = 0.125 * sum_{d'<64} bin_[64h+d']   * Wk2[64h+d'][j]
__global__ __launch_bounds__(256) void prep_wqw2(
    const float* __restrict__ Win, const float* __restrict__ Wk2,
    const float* __restrict__ bin_,
    float* __restrict__ WqW2, float* __restrict__ bqW2)
{
    const int o = blockIdx.x;          // 0..511
    const int h = o >> 7, j = o & 127;
    const int d = threadIdx.x;         // 0..255
    float acc = 0.f;
    for (int dp = 0; dp < 64; ++dp) {
        const float w2 = Wk2[(size_t)(64 * h + dp) * 128 + j];
        acc = fmaf(Win[(size_t)(64 * h + dp) * 256 + d], w2, acc);
    }
    WqW2[(size_t)o * 256 + d] = acc * 0.125f;
    if (d < 64) {
        float pb = bin_[64 * h + d] * Wk2[(size_t)(64 * h + d) * 128 + j];
        #pragma unroll
        for (int off = 1; off < 64; off <<= 1) pb += __shfl_xor(pb, off);
        if (d == 0) bqW2[o] = pb * 0.125f;
    }
}

// ---------------------------------------------------------------------------
// C2: Wcat[o][0:256] = Wout row; Wcat[o][256 + h*128 + jj] = sum_{d'} Wout[o][64h+d'] * Wv2[64h+d'][jj]
__global__ __launch_bounds__(256) void prep_wcat(
    const float* __restrict__ Wout, const float* __restrict__ Wv2,
    float* __restrict__ Wcat)
{
    const int o = blockIdx.x;
    const int t = threadIdx.x;
    Wcat[(size_t)o * 768 + t] = Wout[(size_t)o * 256 + t];
    for (int v = t; v < 512; v += 256) {
        const int h = v >> 7, jj = v & 127;
        const float* wo  = Wout + (size_t)o * 256 + h * 64;
        const float* wv2 = Wv2 + (size_t)(h * 64) * 128 + jj;
        float a = 0.f;
        for (int dp = 0; dp < 64; ++dp) a = fmaf(wo[dp], wv2[(size_t)dp * 128], a);
        Wcat[(size_t)o * 768 + 256 + v] = a;
    }
}

// ---------------------------------------------------------------------------
// Register-tiled fp32 GEMM core: 64x64 tile/block, BK=32, 4x4 acc/thread.
#define GEMM_BODY(XPTR, XSTRIDE, WPTR, KDIM, R0, C0)                          \
    __shared__ float xs[32][65];                                              \
    __shared__ float wsd[32][65];                                             \
    const int tid = threadIdx.x;                                              \
    const int lm = tid >> 5, lk = tid & 31;                                   \
    const int rr = 4 * (tid & 15), cc = 4 * (tid >> 4);                       \
    float acc[4][4] = {{0.f,0.f,0.f,0.f},{0.f,0.f,0.f,0.f},                   \
                       {0.f,0.f,0.f,0.f},{0.f,0.f,0.f,0.f}};                  \
    for (int k0 = 0; k0 < (KDIM); k0 += 32) {                                 \
        __syncthreads();                                                      \
        _Pragma("unroll")                                                     \
        for (int it = 0; it < 8; ++it) {                                      \
            const int m = lm + it * 8;                                        \
            xs[lk][m]  = (XPTR)[(size_t)((R0) + m) * (XSTRIDE) + k0 + lk];    \
            wsd[lk][m] = (WPTR)[(size_t)((C0) + m) * (KDIM) + k0 + lk];       \
        }                                                                     \
        __syncthreads();                                                      \
        _Pragma("unroll")                                                     \
        for (int k = 0; k < 32; ++k) {                                        \
            const float4 xv = *(const float4*)&xs[k][rr];                     \
            const float4 wv = *(const float4*)&wsd[k][cc];                    \
            acc[0][0] = fmaf(xv.x, wv.x, acc[0][0]);                          \
            acc[0][1] = fmaf(xv.x, wv.y, acc[0][1]);                          \
            acc[0][2] = fmaf(xv.x, wv.z, acc[0][2]);                          \
            acc[0][3] = fmaf(xv.x, wv.w, acc[0][3]);                          \
            acc[1][0] = fmaf(xv.y, wv.x, acc[1][0]);                          \
            acc[1][1] = fmaf(xv.y, wv.y, acc[1][1]);                          \
            acc[1][2] = fmaf(xv.y, wv.z, acc[1][2]);                          \
            acc[1][3] = fmaf(xv.y, wv.w, acc[1][3]);                          \
            acc[2][0] = fmaf(xv.z, wv.x, acc[2][0]);                          \
            acc[2][1] = fmaf(xv.z, wv.y, acc[2][1]);                          \
            acc[2][2] = fmaf(xv.z, wv.z, acc[2][2]);                          \
            acc[2][3] = fmaf(xv.z, wv.w, acc[2][3]);                          \
            acc[3][0] = fmaf(xv.w, wv.x, acc[3][0]);                          \
            acc[3][1] = fmaf(xv.w, wv.y, acc[3][1]);                          \
            acc[3][2] = fmaf(xv.w, wv.z, acc[3][2]);                          \
            acc[3][3] = fmaf(xv.w, wv.w, acc[3][3]);                          \
        }                                                                     \
    }

__global__ __launch_bounds__(256) void gemm_plain(
    const float* __restrict__ X, int xstride,
    const float* __restrict__ W, const float* __restrict__ bias,
    float scale, float* __restrict__ Y, int ystride, int K, int ntiles)
{
    const int bid = blockIdx.x;
    const int r0 = (bid / ntiles) * 64;
    const int c0 = (bid % ntiles) * 64;
    GEMM_BODY(X, xstride, W, K, r0, c0)
    float b0 = 0.f, b1 = 0.f, b2 = 0.f, b3 = 0.f;
    if (bias) { b0 = bias[c0+cc+0]; b1 = bias[c0+cc+1]; b2 = bias[c0+cc+2]; b3 = bias[c0+cc+3]; }
    #pragma unroll
    for (int i = 0; i < 4; ++i) {
        float4 o;
        o.x = (acc[i][0] + b0) * scale;
        o.y = (acc[i][1] + b1) * scale;
        o.z = (acc[i][2] + b2) * scale;
        o.w = (acc[i][3] + b3) * scale;
        *(float4*)&Y[(size_t)(r0 + rr + i) * ystride + c0 + cc] = o;
    }
}

// Fused QKV+qW GEMM: X=feat (8192x256), virtual N=1280 in 4 segments.
__global__ __launch_bounds__(256) void gemm_qkvw(
    const float* __restrict__ feat, const float* __restrict__ Win,
    const float* __restrict__ WqW2,
    const float* __restrict__ bin_, const float* __restrict__ bkf,
    const float* __restrict__ bvf, const float* __restrict__ bqW2,
    float* __restrict__ Qm, float* __restrict__ Kp,
    float* __restrict__ Vp, float* __restrict__ qWa)
{
    const int bid = blockIdx.x;
    const int r0 = (bid / 20) * 64;
    const int cg = (bid % 20) * 64;       // global col
    const float* Wb; const float* bb; float scale; float* Yb; int ys; int c0;
    if (cg < 256)      { Wb = Win;             bb = bin_; scale = 0.125f; Yb = Qm;  ys = 256; c0 = cg; }
    else if (cg < 512) { Wb = Win + 256 * 256; bb = bkf;  scale = 1.f;    Yb = Kp;  ys = 256; c0 = cg - 256; }
    else if (cg < 768) { Wb = Win + 512 * 256; bb = bvf;  scale = 1.f;    Yb = Vp;  ys = 256; c0 = cg - 512; }
    else               { Wb = WqW2;            bb = bqW2; scale = 1.f;    Yb = qWa; ys = 512; c0 = cg - 768; }
    GEMM_BODY(feat, 256, Wb, 256, r0, c0)
    const float b0 = bb[c0+cc+0], b1 = bb[c0+cc+1], b2 = bb[c0+cc+2], b3 = bb[c0+cc+3];
    #pragma unroll
    for (int i = 0; i < 4; ++i) {
        float4 o;
        o.x = (acc[i][0] + b0) * scale;
        o.y = (acc[i][1] + b1) * scale;
        o.z = (acc[i][2] + b2) * scale;
        o.w = (acc[i][3] + b3) * scale;
        *(float4*)&Yb[(size_t)(r0 + rr + i) * ys + c0 + cc] = o;
    }
}

// ---------------------------------------------------------------------------
// KNN v3: one wave per point; 4 groups of 16 lanes each extract the sorted
// top-48 of their 1024 candidates via DPP (full-rate VALU) 16-lane argmin
// butterflies + lazy deletion; then a rank-scatter merge of the 4 sorted
// lists via binary count-less in LDS. Key = (distbits<<32)|j: monotone for
// nonneg floats, distinct, lower-index tie-break == jax.lax.top_k.

#define GRPMIN(BASE, OUTKEY) do {                                            \
    unsigned m_ = 0xFFFFFFFFu; int ms_ = (BASE);                             \
    _Pragma("unroll")                                                        \
    for (int s_ = 0; s_ < 16; ++s_) {                                        \
        unsigned v_ = ((dead >> ((BASE) + s_)) & 1ull) ? 0xFFFFFFFFu         \
                                                       : db[(BASE) + s_];    \
        if (v_ < m_) { m_ = v_; ms_ = (BASE) + s_; }                         \
    }                                                                        \
    OUTKEY = ((unsigned long long)m_ << 32) | (unsigned)(ms_ * 64 + lane);   \
} while (0)

static __device__ __forceinline__ unsigned long long umin64(
    unsigned long long a, unsigned long long b) { return a < b ? a : b; }

// one DPP min step on a u64 key (both halves permuted identically)
#define DPP_MIN_STEP(K, CTRL) do {                                           \
    unsigned lo_ = (unsigned)((K) & 0xFFFFFFFFull);                          \
    unsigned hi_ = (unsigned)((K) >> 32);                                    \
    unsigned plo_ = (unsigned)__builtin_amdgcn_update_dpp(                   \
        (int)lo_, (int)lo_, (CTRL), 0xF, 0xF, false);                        \
    unsigned phi_ = (unsigned)__builtin_amdgcn_update_dpp(                   \
        (int)hi_, (int)hi_, (CTRL), 0xF, 0xF, false);                        \
    unsigned long long o_ = ((unsigned long long)phi_ << 32) | plo_;         \
    (K) = o_ < (K) ? o_ : (K);                                               \
} while (0)

__global__ __launch_bounds__(256) void knn_kernel(
    const float* __restrict__ coords, int* __restrict__ nidx, float* __restrict__ ndist)
{
    #pragma clang fp contract(off)
    const int tid = threadIdx.x;
    const int lane = tid & 63;
    const int wv = tid >> 6;
    const int ll = lane & 15;            // lane in 16-group
    const int g  = lane >> 4;            // group 0..3
    const int p = blockIdx.x * 4 + wv;   // one wave per point
    const int b = p >> 12;
    const int i = p & 4095;
    const float* cb = coords + (size_t)b * NPTS * 3;
    const float xi = cb[i * 3 + 0], yi = cb[i * 3 + 1], ti = cb[i * 3 + 2];

    unsigned db[64];
    #pragma unroll
    for (int s = 0; s < 64; ++s) {
        const int j = s * 64 + lane;
        const float xj = cb[j * 3 + 0], yj = cb[j * 3 + 1], tj = cb[j * 3 + 2];
        const float dx = xi - xj, dy = yi - yj;
        const float sd = sqrtf(dx * dx + dy * dy);
        const float dd = sd + 0.3f * fabsf(tj - ti);
        const bool bad = (j == i) || (tj > ti) || (sd > 50.0f);
        db[s] = bad ? 0x7F800000u : __float_as_uint(dd);
    }

    unsigned long long dead = 0ull;
    unsigned long long k0, k1, k2, k3;
    GRPMIN(0,  k0); GRPMIN(16, k1); GRPMIN(32, k2); GRPMIN(48, k3);
    unsigned long long lmin = umin64(umin64(k0, k1), umin64(k2, k3));

    // [wave][group][64]: 48 sorted keys + 16 pad entries of UINT64_MAX
    __shared__ unsigned long long gk[4][4][64];
    gk[wv][g][48 + ll] = 0xFFFFFFFFFFFFFFFFull;

    for (int k = 0; k < KK; ++k) {
        unsigned long long kb = lmin;
        DPP_MIN_STEP(kb, 0x0B1);   // quad_perm [1,0,3,2]  (xor 1)
        DPP_MIN_STEP(kb, 0x04E);   // quad_perm [2,3,0,1]  (xor 2)
        DPP_MIN_STEP(kb, 0x141);   // ROW_HALF_MIRROR      (8-group exchange)
        DPP_MIN_STEP(kb, 0x140);   // ROW_MIRROR           (16-group exchange)
        if (ll == (k & 15)) gk[wv][g][k] = kb;   // one lane/group stores rank-k
        const int wj = (int)(kb & 0xFFFFFFFFull);
        if ((wj & 63) == lane) {                 // owner lane rescans
            const int ws = wj >> 6;
            dead |= (1ull << ws);
            const int gg = ws >> 4;
            if      (gg == 0) GRPMIN(0,  k0);
            else if (gg == 1) GRPMIN(16, k1);
            else if (gg == 2) GRPMIN(32, k2);
            else              GRPMIN(48, k3);
            lmin = umin64(umin64(k0, k1), umin64(k2, k3));
        }
    }
    __syncthreads();

    // rank-scatter merge: rank(e) = sum over all 4 sorted lists of count_less(e)
    // (own-list count equals own position since keys are distinct)
    #pragma unroll
    for (int e = 0; e < 3; ++e) {
        const int myi = ll + e * 16;
        const unsigned long long key = gk[wv][g][myi];
        int rank = 0;
        #pragma unroll
        for (int gg = 0; gg < 4; ++gg) {
            const unsigned long long* arr = &gk[wv][gg][0];
            int c = 0;
            #pragma unroll
            for (int s = 32; s >= 1; s >>= 1)
                if (arr[c + s - 1] < key) c += s;
            rank += c;
        }
        if (rank < KK) {
            ndist[(size_t)p * KK + rank] = __uint_as_float((unsigned)(key >> 32));
            nidx [(size_t)p * KK + rank] = (int)(key & 0xFFFFFFFFull);
        }
    }
}

// ---------------------------------------------------------------------------
// E2: per-point attention core + gate. Writes vh[p][0:256]=vbar_flat, [256:768]=hbar_flat,
// both already multiplied by ring gate weights; nonb flag for the no-neighbor case.
__global__ __launch_bounds__(256) void attn_kernel(
    const float* __restrict__ coords, const float* __restrict__ Q,
    const float* __restrict__ Kp, const float* __restrict__ Vp,
    const float* __restrict__ qWa,
    const int* __restrict__ nidx, const float* __restrict__ ndist,
    const float* __restrict__ Wpe1, const float* __restrict__ bpe1,
    const float* __restrict__ Wg1, const float* __restrict__ bg1,
    const float* __restrict__ Wg2, const float* __restrict__ bg2,
    float* __restrict__ vh, unsigned char* __restrict__ nonb)
{
    const int p = blockIdx.x;
    const int b = p >> 12;
    const int i = p & 4095;
    const int tid = threadIdx.x;

    __shared__ __align__(16) float qs[4][68];     // padded
    __shared__ __align__(16) float qw[4][132];    // padded
    __shared__ __align__(16) float rel[KK][4];
    __shared__ float kd[KK];
    __shared__ int   sidx[KK];
    __shared__ int   svalid[KK];
    __shared__ __align__(16) float hid[KK][132];  // padded
    __shared__ float wsh[KK][4];
    __shared__ float wring[4];

    // phase 0+1: loads
    for (int v = tid; v < 256; v += 256) qs[v >> 6][v & 63] = Q[(size_t)p * 256 + v];
    for (int v = tid; v < 512; v += 256) qw[v >> 7][v & 127] = qWa[(size_t)p * 512 + v];
    const float* cb = coords + (size_t)b * NPTS * 3;
    const float xi = cb[i * 3 + 0], yi = cb[i * 3 + 1], ti = cb[i * 3 + 2];
    if (tid < KK) {
        const float dd = ndist[(size_t)p * KK + tid];
        const int ix = nidx[(size_t)p * KK + tid];
        sidx[tid] = ix;
        const int val = (dd < 3.0e38f) ? 1 : 0;
        svalid[tid] = val;
        const float kdd = val ? dd : 0.f;
        kd[tid] = kdd;
        rel[tid][0] = cb[ix * 3 + 0] - xi;
        rel[tid][1] = cb[ix * 3 + 1] - yi;
        rel[tid][2] = cb[ix * 3 + 2] - ti;
        rel[tid][3] = kdd;
    }
    __syncthreads();

    // phase 2: wave 0 computes gate; all waves then compute hidden
    if (tid < 64) {
        const int val = (tid < KK) ? svalid[tid] : 0;
        float dtv = 0.f;
        if (tid < KK && val) dtv = fabsf(rel[tid][2]);
        const unsigned long long m = __ballot(val != 0);
        const int count = __popcll(m);
        const int vc = count > 0 ? count : 1;
        float sdt = dtv;
        #pragma unroll
        for (int off = 1; off < 64; off <<= 1) sdt += __shfl_xor(sdt, off);
        const float vcf = (float)vc;
        const float dtmean = sdt / vcf;
        float dq = 0.f;
        if (tid < KK && val) { float tq = dtv - dtmean; dq = tq * tq; }
        float sdq = dq;
        #pragma unroll
        for (int off = 1; off < 64; off <<= 1) sdq += __shfl_xor(sdq, off);
        const float dtstd = sqrtf(sdq / vcf + 1e-8f);
        const float dens = kd[vc - 1];
        const float g0 = fminf(fmaxf(dens / (dens + 1e-6f), 0.f), 10.f);
        const float g1v = fminf(fmaxf(vcf / 48.f, 0.f), 1.f);
        const float g2 = fminf(fmaxf(dtmean / (dtmean + 1e-6f), 0.f), 10.f);
        const float g3 = fminf(fmaxf(dtstd / (dtstd + 1e-6f), 0.f), 10.f);
        float gh = 0.f;
        if (tid < 32) {
            gh = bg1[tid] + g0 * Wg1[tid * 4 + 0] + g1v * Wg1[tid * 4 + 1]
               + g2 * Wg1[tid * 4 + 2] + g3 * Wg1[tid * 4 + 3];
            gh = fmaxf(gh, 0.f);
        }
        float gl[3];
        #pragma unroll
        for (int r = 0; r < 3; ++r) {
            float part = (tid < 32) ? gh * Wg2[r * 32 + tid] : 0.f;
            #pragma unroll
            for (int off = 1; off < 64; off <<= 1) part += __shfl_xor(part, off);
            gl[r] = part + bg2[r];
        }
        if (count < 1)  gl[0] = -INFINITY;
        if (count < 17) gl[1] = -INFINITY;
        if (count < 33) gl[2] = -INFINITY;
        float w0 = 0.f, w1 = 0.f, w2 = 0.f;
        if (count > 0) {
            const float mx = fmaxf(gl[0], fmaxf(gl[1], gl[2]));
            const float e0 = expf(gl[0] - mx), e1 = expf(gl[1] - mx), e2 = expf(gl[2] - mx);
            const float es = e0 + e1 + e2;
            w0 = e0 / es; w1 = e1 / es; w2 = e2 / es;
        }
        if (tid == 0) {
            wring[0] = w0; wring[1] = w1; wring[2] = w2;
            nonb[p] = (count == 0) ? (unsigned char)1 : (unsigned char)0;
        }
    }
    // hidden: 48x128, relu(Wpe1 @ rel + bpe1)
    for (int v = tid; v < KK * 128; v += 256) {
        const int s = v >> 7, jj = v & 127;
        const float4 r4 = *(const float4*)(&rel[s][0]);
        const float4 w4 = *(const float4*)(Wpe1 + (size_t)jj * 4);
        float hdd = bpe1[jj] + r4.x * w4.x + r4.y * w4.y + r4.z * w4.z + r4.w * w4.w;
        hid[s][jj] = fmaxf(hdd, 0.f);
    }
    __syncthreads();

    // phase 3: logits + per-ring softmax (wave r owns ring r)
    if (tid < 192) {
        const int s_ = tid >> 2, h_ = tid & 3;
        float acc = 0.f;
        const float4* hp = (const float4*)(&hid[s_][0]);
        const float4* qp = (const float4*)(&qw[h_][0]);
        #pragma unroll
        for (int j4 = 0; j4 < 32; ++j4) {
            float4 hv = hp[j4], qv = qp[j4];
            acc = fmaf(qv.x, hv.x, fmaf(qv.y, hv.y, fmaf(qv.z, hv.z, fmaf(qv.w, hv.w, acc))));
        }
        const float* kr = Kp + ((size_t)b * NPTS + sidx[s_]) * 256 + h_ * 64;
        const float4* qsp = (const float4*)(&qs[h_][0]);
        #pragma unroll
        for (int d4 = 0; d4 < 16; ++d4) {
            float4 kv = *(const float4*)(kr + d4 * 4);
            float4 qv = qsp[d4];
            acc = fmaf(qv.x, kv.x, fmaf(qv.y, kv.y, fmaf(qv.z, kv.z, fmaf(qv.w, kv.w, acc))));
        }
        float logit = svalid[s_] ? acc : -1e9f;
        float mx = logit;
        #pragma unroll
        for (int off = 4; off < 64; off <<= 1) mx = fmaxf(mx, __shfl_xor(mx, off));
        const float e = expf(logit - mx);
        float es = e;
        #pragma unroll
        for (int off = 4; off < 64; off <<= 1) es += __shfl_xor(es, off);
        wsh[s_][h_] = (e / es) * wring[tid >> 6];
    }
    __syncthreads();

    // phase 4: vbar -> vh[p][0:256]  (4 independent gather chains for ILP)
    {
        const int h = tid >> 6, dp = tid & 63;
        const size_t bb = (size_t)b * NPTS;
        const float* vpb = Vp + h * 64 + dp;
        float a0 = 0.f, a1 = 0.f, a2 = 0.f, a3 = 0.f;
        #pragma unroll
        for (int s = 0; s < 12; ++s) {
            a0 = fmaf(wsh[s     ][h], vpb[(bb + sidx[s     ]) * 256], a0);
            a1 = fmaf(wsh[s + 12][h], vpb[(bb + sidx[s + 12]) * 256], a1);
            a2 = fmaf(wsh[s + 24][h], vpb[(bb + sidx[s + 24]) * 256], a2);
            a3 = fmaf(wsh[s + 36][h], vpb[(bb + sidx[s + 36]) * 256], a3);
        }
        vh[(size_t)p * 768 + tid] = (a0 + a1) + (a2 + a3);
    }
    // phase 5: hbar -> vh[p][256:768]  (2 chains)
    for (int v = tid; v < 512; v += 256) {
        const int h = v >> 7, jj = v & 127;
        float a0 = 0.f, a1 = 0.f;
        #pragma unroll
        for (int s = 0; s < 24; ++s) {
            a0 = fmaf(wsh[s     ][h], hid[s     ][jj], a0);
            a1 = fmaf(wsh[s + 24][h], hid[s + 24][jj], a1);
        }
        vh[(size_t)p * 768 + 256 + v] = a0 + a1;
    }
}

// ---------------------------------------------------------------------------
// E3b: LayerNorm epilogue: x = xo + (nonb?0:bout) + feat; LN; out.
__global__ __launch_bounds__(256) void ln_kernel(
    const float* __restrict__ xo, const float* __restrict__ feat,
    const float* __restrict__ bout, const unsigned char* __restrict__ nonb,
    const float* __restrict__ gamma, const float* __restrict__ beta,
    float* __restrict__ out)
{
    const int lane = threadIdx.x & 63;
    const int p = blockIdx.x * 4 + (threadIdx.x >> 6);
    const float4 xv = *(const float4*)&xo  [(size_t)p * 256 + lane * 4];
    const float4 fv = *(const float4*)&feat[(size_t)p * 256 + lane * 4];
    const float4 bv = *(const float4*)&bout[lane * 4];
    const float bm = nonb[p] ? 0.f : 1.f;
    float x0 = xv.x + fv.x + bm * bv.x;
    float x1 = xv.y + fv.y + bm * bv.y;
    float x2 = xv.z + fv.z + bm * bv.z;
    float x3 = xv.w + fv.w + bm * bv.w;
    float s1 = x0 + x1 + x2 + x3;
    float s2 = fmaf(x0, x0, fmaf(x1, x1, fmaf(x2, x2, x3 * x3)));
    #pragma unroll
    for (int off = 1; off < 64; off <<= 1) {
        s1 += __shfl_xor(s1, off);
        s2 += __shfl_xor(s2, off);
    }
    const float mu = s1 * (1.f / 256.f);
    const float var = s2 * (1.f / 256.f) - mu * mu;
    const float rs = 1.f / sqrtf(var + 1e-5f);
    const float4 gv = *(const float4*)&gamma[lane * 4];
    const float4 tv = *(const float4*)&beta [lane * 4];
    float4 o;
    o.x = (x0 - mu) * rs * gv.x + tv.x;
    o.y = (x1 - mu) * rs * gv.y + tv.y;
    o.z = (x2 - mu) * rs * gv.z + tv.z;
    o.w = (x3 - mu) * rs * gv.w + tv.w;
    *(float4*)&out[(size_t)p * 256 + lane * 4] = o;
}

// ---------------------------------------------------------------------------
extern "C" void kernel_launch(void* const* d_in, const int* in_sizes, int n_in,
                              void* d_out, int out_size, void* d_ws, size_t ws_size,
                              hipStream_t stream) {
    (void)in_sizes; (void)n_in; (void)out_size; (void)ws_size;
    const float* features = (const float*)d_in[0];
    const float* coords   = (const float*)d_in[1];
    const float* Wfeat    = (const float*)d_in[2];
    const float* bfeat    = (const float*)d_in[3];
    const float* Wpe1     = (const float*)d_in[4];
    const float* bpe1     = (const float*)d_in[5];
    const float* Wpe2     = (const float*)d_in[6];
    const float* bpe2     = (const float*)d_in[7];
    const float* Win      = (const float*)d_in[8];
    const float* bin_     = (const float*)d_in[9];
    const float* Wout     = (const float*)d_in[10];
    const float* bout     = (const float*)d_in[11];
    const float* Wg1      = (const float*)d_in[12];
    const float* bg1      = (const float*)d_in[13];
    const float* Wg2      = (const float*)d_in[14];
    const float* bg2      = (const float*)d_in[15];
    const float* gamma    = (const float*)d_in[16];
    const float* beta     = (const float*)d_in[17];
    float* out = (float*)d_out;

    // workspace layout (floats); ~76 MB (xo aliases Qm — dead after attn)
    float* ws   = (float*)d_ws;
    float* feat = ws;
    float* Qm   = feat + (size_t)NB * DM;
    float* Kp   = Qm   + (size_t)NB * DM;
    float* Vp   = Kp   + (size_t)NB * DM;
    float* qWa  = Vp   + (size_t)NB * DM;
    float* vh   = qWa  + (size_t)NB * 512;
    float* Wk2  = vh   + (size_t)NB * 768;
    float* Wv2  = Wk2  + 256 * 128;
    float* Wcat = Wv2  + 256 * 128;
    float* WqW2 = Wcat + 256 * 768;
    float* bkf  = WqW2 + 512 * 256;
    float* bvf  = bkf + 256;
    float* bqW2 = bvf + 256;
    float* ndist = bqW2 + 512;
    int*   nidx = (int*)(ndist + (size_t)NB * KK);
    unsigned char* nonb = (unsigned char*)(nidx + (size_t)NB * KK);
    float* xo   = Qm;   // alias: Qm dead after attn_kernel

    prep_wkv2<<<256, 128, 0, stream>>>(Win, Wpe2, bpe2, bin_, Wk2, Wv2, bkf, bvf);
    prep_wqw2<<<512, 256, 0, stream>>>(Win, Wk2, bin_, WqW2, bqW2);
    prep_wcat<<<256, 256, 0, stream>>>(Wout, Wv2, Wcat);

    // feat = features @ Wfeat^T + bfeat
    gemm_plain<<<(NB / 64) * 4, 256, 0, stream>>>(
        features, 256, Wfeat, bfeat, 1.0f, feat, 256, 256, 4);

    // fused Q/K/V/qW
    gemm_qkvw<<<(NB / 64) * 20, 256, 0, stream>>>(
        feat, Win, WqW2, bin_, bkf, bvf, bqW2, Qm, Kp, Vp, qWa);

    knn_kernel<<<NB / 4, 256, 0, stream>>>(coords, nidx, ndist);

    attn_kernel<<<NB, 256, 0, stream>>>(coords, Qm, Kp, Vp, qWa, nidx, ndist,
                                        Wpe1, bpe1, Wg1, bg1, Wg2, bg2, vh, nonb);

    // xo = vh @ Wcat^T   (bias/residual/LN handled by ln_kernel)
    gemm_plain<<<(NB / 64) * 4, 256, 0, stream>>>(
        vh, 768, Wcat, nullptr, 1.0f, xo, 256, 768, 4);

    ln_kernel<<<NB / 4, 256, 0, stream>>>(xo, feat, bout, nonb, gamma, beta, out);
}

// Round 13
// 584.278 us; speedup vs baseline: 1.1884x; 1.1884x over previous
//
#include <hip/hip_runtime.h>
#include <cmath>

#define NPTS 4096
#define NB   8192      // B*N
#define DM   256
#define KK   48

// ---------------------------------------------------------------------------
// C1: Wk2 = Wk@Wpe2, Wv2 = Wv@Wpe2 (256x128 each); bkf = bk + Wk@bpe2, bvf likewise
__global__ __launch_bounds__(128) void prep_wkv2(
    const float* __restrict__ Win, const float* __restrict__ Wpe2,
    const float* __restrict__ bpe2, const float* __restrict__ bin_,
    float* __restrict__ Wk2, float* __restrict__ Wv2,
    float* __restrict__ bkf, float* __restrict__ bvf)
{
    const int o = blockIdx.x;          // 0..255 output row
    const int j = threadIdx.x;         // 0..127
    const float* wk = Win + (size_t)(256 + o) * 256;
    const float* wv = Win + (size_t)(512 + o) * 256;
    float ak = 0.f, av = 0.f;
    for (int d = 0; d < 256; ++d) {
        float pw = Wpe2[(size_t)d * 128 + j];
        ak = fmaf(wk[d], pw, ak);
        av = fmaf(wv[d], pw, av);
    }
    Wk2[(size_t)o * 128 + j] = ak;
    Wv2[(size_t)o * 128 + j] = av;

    __shared__ float pk[128], pv[128];
    pk[j] = wk[j] * bpe2[j] + wk[j + 128] * bpe2[j + 128];
    pv[j] = wv[j] * bpe2[j] + wv[j + 128] * bpe2[j + 128];
    __syncthreads();
    for (int off = 64; off >= 1; off >>= 1) {
        if (j < off) { pk[j] += pk[j + off]; pv[j] += pv[j + off]; }
        __syncthreads();
    }
    if (j == 0) {
        bkf[o] = bin_[256 + o] + pk[0];
        bvf[o] = bin_[512 + o] + pv[0];
    }
}

// ---------------------------------------------------------------------------
// C1b: WqW2[o=h*128+j][d] = 0.125 * sum_{d'<64} Win[64h+d'][d] * Wk2[64h+d'][j]
//      bqW2[o]            = 0.125 * sum_{d'<64} bin_[64h+d']   * Wk2[64h+d'][j]
__global__ __launch_bounds__(256) void prep_wqw2(
    const float* __restrict__ Win, const float* __restrict__ Wk2,
    const float* __restrict__ bin_,
    float* __restrict__ WqW2, float* __restrict__ bqW2)
{
    const int o = blockIdx.x;          // 0..511
    const int h = o >> 7, j = o & 127;
    const int d = threadIdx.x;         // 0..255
    float acc = 0.f;
    for (int dp = 0; dp < 64; ++dp) {
        const float w2 = Wk2[(size_t)(64 * h + dp) * 128 + j];
        acc = fmaf(Win[(size_t)(64 * h + dp) * 256 + d], w2, acc);
    }
    WqW2[(size_t)o * 256 + d] = acc * 0.125f;
    if (d < 64) {
        float pb = bin_[64 * h + d] * Wk2[(size_t)(64 * h + d) * 128 + j];
        #pragma unroll
        for (int off = 1; off < 64; off <<= 1) pb += __shfl_xor(pb, off);
        if (d == 0) bqW2[o] = pb * 0.125f;
    }
}

// ---------------------------------------------------------------------------
// C2: Wcat[o][0:256] = Wout row; Wcat[o][256 + h*128 + jj] = sum_{d'} Wout[o][64h+d'] * Wv2[64h+d'][jj]
__global__ __launch_bounds__(256) void prep_wcat(
    const float* __restrict__ Wout, const float* __restrict__ Wv2,
    float* __restrict__ Wcat)
{
    const int o = blockIdx.x;
    const int t = threadIdx.x;
    Wcat[(size_t)o * 768 + t] = Wout[(size_t)o * 256 + t];
    for (int v = t; v < 512; v += 256) {
        const int h = v >> 7, jj = v & 127;
        const float* wo  = Wout + (size_t)o * 256 + h * 64;
        const float* wv2 = Wv2 + (size_t)(h * 64) * 128 + jj;
        float a = 0.f;
        for (int dp = 0; dp < 64; ++dp) a = fmaf(wo[dp], wv2[(size_t)dp * 128], a);
        Wcat[(size_t)o * 768 + 256 + v] = a;
    }
}

// ---------------------------------------------------------------------------
// Register-tiled fp32 GEMM core: 64x64 tile/block, BK=32, 4x4 acc/thread.
#define GEMM_BODY(XPTR, XSTRIDE, WPTR, KDIM, R0, C0)                          \
    __shared__ float xs[32][65];                                              \
    __shared__ float wsd[32][65];                                             \
    const int tid = threadIdx.x;                                              \
    const int lm = tid >> 5, lk = tid & 31;                                   \
    const int rr = 4 * (tid & 15), cc = 4 * (tid >> 4);                       \
    float acc[4][4] = {{0.f,0.f,0.f,0.f},{0.f,0.f,0.f,0.f},                   \
                       {0.f,0.f,0.f,0.f},{0.f,0.f,0.f,0.f}};                  \
    for (int k0 = 0; k0 < (KDIM); k0 += 32) {                                 \
        __syncthreads();                                                      \
        _Pragma("unroll")                                                     \
        for (int it = 0; it < 8; ++it) {                                      \
            const int m = lm + it * 8;                                        \
            xs[lk][m]  = (XPTR)[(size_t)((R0) + m) * (XSTRIDE) + k0 + lk];    \
            wsd[lk][m] = (WPTR)[(size_t)((C0) + m) * (KDIM) + k0 + lk];       \
        }                                                                     \
        __syncthreads();                                                      \
        _Pragma("unroll")                                                     \
        for (int k = 0; k < 32; ++k) {                                        \
            const float4 xv = *(const float4*)&xs[k][rr];                     \
            const float4 wv = *(const float4*)&wsd[k][cc];                    \
            acc[0][0] = fmaf(xv.x, wv.x, acc[0][0]);                          \
            acc[0][1] = fmaf(xv.x, wv.y, acc[0][1]);                          \
            acc[0][2] = fmaf(xv.x, wv.z, acc[0][2]);                          \
            acc[0][3] = fmaf(xv.x, wv.w, acc[0][3]);                          \
            acc[1][0] = fmaf(xv.y, wv.x, acc[1][0]);                          \
            acc[1][1] = fmaf(xv.y, wv.y, acc[1][1]);                          \
            acc[1][2] = fmaf(xv.y, wv.z, acc[1][2]);                          \
            acc[1][3] = fmaf(xv.y, wv.w, acc[1][3]);                          \
            acc[2][0] = fmaf(xv.z, wv.x, acc[2][0]);                          \
            acc[2][1] = fmaf(xv.z, wv.y, acc[2][1]);                          \
            acc[2][2] = fmaf(xv.z, wv.z, acc[2][2]);                          \
            acc[2][3] = fmaf(xv.z, wv.w, acc[2][3]);                          \
            acc[3][0] = fmaf(xv.w, wv.x, acc[3][0]);                          \
            acc[3][1] = fmaf(xv.w, wv.y, acc[3][1]);                          \
            acc[3][2] = fmaf(xv.w, wv.z, acc[3][2]);                          \
            acc[3][3] = fmaf(xv.w, wv.w, acc[3][3]);                          \
        }                                                                     \
    }

__global__ __launch_bounds__(256) void gemm_plain(
    const float* __restrict__ X, int xstride,
    const float* __restrict__ W, const float* __restrict__ bias,
    float scale, float* __restrict__ Y, int ystride, int K, int ntiles)
{
    const int bid = blockIdx.x;
    const int r0 = (bid / ntiles) * 64;
    const int c0 = (bid % ntiles) * 64;
    GEMM_BODY(X, xstride, W, K, r0, c0)
    float b0 = 0.f, b1 = 0.f, b2 = 0.f, b3 = 0.f;
    if (bias) { b0 = bias[c0+cc+0]; b1 = bias[c0+cc+1]; b2 = bias[c0+cc+2]; b3 = bias[c0+cc+3]; }
    #pragma unroll
    for (int i = 0; i < 4; ++i) {
        float4 o;
        o.x = (acc[i][0] + b0) * scale;
        o.y = (acc[i][1] + b1) * scale;
        o.z = (acc[i][2] + b2) * scale;
        o.w = (acc[i][3] + b3) * scale;
        *(float4*)&Y[(size_t)(r0 + rr + i) * ystride + c0 + cc] = o;
    }
}

// Fused QKV+qW GEMM: X=feat (8192x256), virtual N=1280 in 4 segments.
__global__ __launch_bounds__(256) void gemm_qkvw(
    const float* __restrict__ feat, const float* __restrict__ Win,
    const float* __restrict__ WqW2,
    const float* __restrict__ bin_, const float* __restrict__ bkf,
    const float* __restrict__ bvf, const float* __restrict__ bqW2,
    float* __restrict__ Qm, float* __restrict__ Kp,
    float* __restrict__ Vp, float* __restrict__ qWa)
{
    const int bid = blockIdx.x;
    const int r0 = (bid / 20) * 64;
    const int cg = (bid % 20) * 64;       // global col
    const float* Wb; const float* bb; float scale; float* Yb; int ys; int c0;
    if (cg < 256)      { Wb = Win;             bb = bin_; scale = 0.125f; Yb = Qm;  ys = 256; c0 = cg; }
    else if (cg < 512) { Wb = Win + 256 * 256; bb = bkf;  scale = 1.f;    Yb = Kp;  ys = 256; c0 = cg - 256; }
    else if (cg < 768) { Wb = Win + 512 * 256; bb = bvf;  scale = 1.f;    Yb = Vp;  ys = 256; c0 = cg - 512; }
    else               { Wb = WqW2;            bb = bqW2; scale = 1.f;    Yb = qWa; ys = 512; c0 = cg - 768; }
    GEMM_BODY(feat, 256, Wb, 256, r0, c0)
    const float b0 = bb[c0+cc+0], b1 = bb[c0+cc+1], b2 = bb[c0+cc+2], b3 = bb[c0+cc+3];
    #pragma unroll
    for (int i = 0; i < 4; ++i) {
        float4 o;
        o.x = (acc[i][0] + b0) * scale;
        o.y = (acc[i][1] + b1) * scale;
        o.z = (acc[i][2] + b2) * scale;
        o.w = (acc[i][3] + b3) * scale;
        *(float4*)&Yb[(size_t)(r0 + rr + i) * ys + c0 + cc] = o;
    }
}

// ---------------------------------------------------------------------------
// KNN v4: one wave per point, v2's single-winner-per-iteration semantics
// (exactly ONE owner lane rescans per extraction -> one GRPMIN body), with
// the 64-lane reduction done via the canonical gfx9 6-step DPP min-reduce
// (VALU-rate, no LDS, no ds_bpermute latency chain):
//   quad xor1, quad xor2, row_half_mirror, row_mirror -> row min (16)
//   row_bcast15, row_bcast31 -> lane 63 holds the 64-lane min
// then 2x readlane broadcasts the u64 winner key to all lanes via SGPR.
// Key = (distbits<<32)|j: monotone for nonneg floats, distinct, lower-index
// tie-break == jax.lax.top_k. v3's DPP encodings verified on HW (R11 passed).

#define GRPMIN(BASE, OUTKEY) do {                                            \
    unsigned m_ = 0xFFFFFFFFu; int ms_ = (BASE);                             \
    _Pragma("unroll")                                                        \
    for (int s_ = 0; s_ < 16; ++s_) {                                        \
        unsigned v_ = ((dead >> ((BASE) + s_)) & 1ull) ? 0xFFFFFFFFu         \
                                                       : db[(BASE) + s_];    \
        if (v_ < m_) { m_ = v_; ms_ = (BASE) + s_; }                         \
    }                                                                        \
    OUTKEY = ((unsigned long long)m_ << 32) | (unsigned)(ms_ * 64 + lane);   \
} while (0)

static __device__ __forceinline__ unsigned long long umin64(
    unsigned long long a, unsigned long long b) { return a < b ? a : b; }

// one DPP min step on a u64 key (both halves permuted identically)
#define DPP_MIN_STEP(K, CTRL) do {                                           \
    unsigned lo_ = (unsigned)((K) & 0xFFFFFFFFull);                          \
    unsigned hi_ = (unsigned)((K) >> 32);                                    \
    unsigned plo_ = (unsigned)__builtin_amdgcn_update_dpp(                   \
        (int)lo_, (int)lo_, (CTRL), 0xF, 0xF, false);                        \
    unsigned phi_ = (unsigned)__builtin_amdgcn_update_dpp(                   \
        (int)hi_, (int)hi_, (CTRL), 0xF, 0xF, false);                        \
    unsigned long long o_ = ((unsigned long long)phi_ << 32) | plo_;         \
    (K) = o_ < (K) ? o_ : (K);                                               \
} while (0)

__global__ __launch_bounds__(256) void knn_kernel(
    const float* __restrict__ coords, int* __restrict__ nidx, float* __restrict__ ndist)
{
    #pragma clang fp contract(off)
    const int lane = threadIdx.x & 63;
    const int p = blockIdx.x * 4 + (threadIdx.x >> 6);   // one wave per point
    const int b = p >> 12;
    const int i = p & 4095;
    const float* cb = coords + (size_t)b * NPTS * 3;
    const float xi = cb[i * 3 + 0], yi = cb[i * 3 + 1], ti = cb[i * 3 + 2];

    unsigned db[64];
    #pragma unroll
    for (int s = 0; s < 64; ++s) {
        const int j = s * 64 + lane;
        const float xj = cb[j * 3 + 0], yj = cb[j * 3 + 1], tj = cb[j * 3 + 2];
        const float dx = xi - xj, dy = yi - yj;
        const float sd = sqrtf(dx * dx + dy * dy);
        const float dd = sd + 0.3f * fabsf(tj - ti);
        const bool bad = (j == i) || (tj > ti) || (sd > 50.0f);
        db[s] = bad ? 0x7F800000u : __float_as_uint(dd);
    }

    unsigned long long dead = 0ull;
    unsigned long long k0, k1, k2, k3;
    GRPMIN(0,  k0); GRPMIN(16, k1); GRPMIN(32, k2); GRPMIN(48, k3);
    unsigned long long lmin = umin64(umin64(k0, k1), umin64(k2, k3));

    unsigned long long reskey = 0ull;
    for (int k = 0; k < KK; ++k) {
        unsigned long long kb = lmin;
        DPP_MIN_STEP(kb, 0x0B1);   // quad_perm [1,0,3,2]  (xor 1)
        DPP_MIN_STEP(kb, 0x04E);   // quad_perm [2,3,0,1]  (xor 2)
        DPP_MIN_STEP(kb, 0x141);   // ROW_HALF_MIRROR      (8-lane exchange)
        DPP_MIN_STEP(kb, 0x140);   // ROW_MIRROR           (16-lane row min)
        DPP_MIN_STEP(kb, 0x142);   // ROW_BCAST15          (32-lane combine)
        DPP_MIN_STEP(kb, 0x143);   // ROW_BCAST31          (64-lane, lane 63)
        const unsigned klo = (unsigned)__builtin_amdgcn_readlane(
            (int)(unsigned)(kb & 0xFFFFFFFFull), 63);
        const unsigned khi = (unsigned)__builtin_amdgcn_readlane(
            (int)(unsigned)(kb >> 32), 63);
        const unsigned long long sk = ((unsigned long long)khi << 32) | klo;
        if (lane == k) reskey = sk;                // lane k keeps result k
        const int wj = (int)klo;                   // winning candidate idx
        if ((wj & 63) == lane) {                   // ONE owner lane rescans
            const int ws = wj >> 6;
            dead |= (1ull << ws);
            const int g = ws >> 4;
            if      (g == 0) GRPMIN(0,  k0);
            else if (g == 1) GRPMIN(16, k1);
            else if (g == 2) GRPMIN(32, k2);
            else             GRPMIN(48, k3);
            lmin = umin64(umin64(k0, k1), umin64(k2, k3));
        }
    }

    if (lane < KK) {
        ndist[(size_t)p * KK + lane] = __uint_as_float((unsigned)(reskey >> 32));
        nidx [(size_t)p * KK + lane] = (int)(reskey & 0xFFFFFFFFull);
    }
}

// ---------------------------------------------------------------------------
// E2: per-point attention core + gate. Writes vh[p][0:256]=vbar_flat, [256:768]=hbar_flat,
// both already multiplied by ring gate weights; nonb flag for the no-neighbor case.
__global__ __launch_bounds__(256) void attn_kernel(
    const float* __restrict__ coords, const float* __restrict__ Q,
    const float* __restrict__ Kp, const float* __restrict__ Vp,
    const float* __restrict__ qWa,
    const int* __restrict__ nidx, const float* __restrict__ ndist,
    const float* __restrict__ Wpe1, const float* __restrict__ bpe1,
    const float* __restrict__ Wg1, const float* __restrict__ bg1,
    const float* __restrict__ Wg2, const float* __restrict__ bg2,
    float* __restrict__ vh, unsigned char* __restrict__ nonb)
{
    const int p = blockIdx.x;
    const int b = p >> 12;
    const int i = p & 4095;
    const int tid = threadIdx.x;

    __shared__ __align__(16) float qs[4][68];     // padded
    __shared__ __align__(16) float qw[4][132];    // padded
    __shared__ __align__(16) float rel[KK][4];
    __shared__ float kd[KK];
    __shared__ int   sidx[KK];
    __shared__ int   svalid[KK];
    __shared__ __align__(16) float hid[KK][132];  // padded
    __shared__ float wsh[KK][4];
    __shared__ float wring[4];

    // phase 0+1: loads
    for (int v = tid; v < 256; v += 256) qs[v >> 6][v & 63] = Q[(size_t)p * 256 + v];
    for (int v = tid; v < 512; v += 256) qw[v >> 7][v & 127] = qWa[(size_t)p * 512 + v];
    const float* cb = coords + (size_t)b * NPTS * 3;
    const float xi = cb[i * 3 + 0], yi = cb[i * 3 + 1], ti = cb[i * 3 + 2];
    if (tid < KK) {
        const float dd = ndist[(size_t)p * KK + tid];
        const int ix = nidx[(size_t)p * KK + tid];
        sidx[tid] = ix;
        const int val = (dd < 3.0e38f) ? 1 : 0;
        svalid[tid] = val;
        const float kdd = val ? dd : 0.f;
        kd[tid] = kdd;
        rel[tid][0] = cb[ix * 3 + 0] - xi;
        rel[tid][1] = cb[ix * 3 + 1] - yi;
        rel[tid][2] = cb[ix * 3 + 2] - ti;
        rel[tid][3] = kdd;
    }
    __syncthreads();

    // phase 2: wave 0 computes gate; all waves then compute hidden
    if (tid < 64) {
        const int val = (tid < KK) ? svalid[tid] : 0;
        float dtv = 0.f;
        if (tid < KK && val) dtv = fabsf(rel[tid][2]);
        const unsigned long long m = __ballot(val != 0);
        const int count = __popcll(m);
        const int vc = count > 0 ? count : 1;
        float sdt = dtv;
        #pragma unroll
        for (int off = 1; off < 64; off <<= 1) sdt += __shfl_xor(sdt, off);
        const float vcf = (float)vc;
        const float dtmean = sdt / vcf;
        float dq = 0.f;
        if (tid < KK && val) { float tq = dtv - dtmean; dq = tq * tq; }
        float sdq = dq;
        #pragma unroll
        for (int off = 1; off < 64; off <<= 1) sdq += __shfl_xor(sdq, off);
        const float dtstd = sqrtf(sdq / vcf + 1e-8f);
        const float dens = kd[vc - 1];
        const float g0 = fminf(fmaxf(dens / (dens + 1e-6f), 0.f), 10.f);
        const float g1v = fminf(fmaxf(vcf / 48.f, 0.f), 1.f);
        const float g2 = fminf(fmaxf(dtmean / (dtmean + 1e-6f), 0.f), 10.f);
        const float g3 = fminf(fmaxf(dtstd / (dtstd + 1e-6f), 0.f), 10.f);
        float gh = 0.f;
        if (tid < 32) {
            gh = bg1[tid] + g0 * Wg1[tid * 4 + 0] + g1v * Wg1[tid * 4 + 1]
               + g2 * Wg1[tid * 4 + 2] + g3 * Wg1[tid * 4 + 3];
            gh = fmaxf(gh, 0.f);
        }
        float gl[3];
        #pragma unroll
        for (int r = 0; r < 3; ++r) {
            float part = (tid < 32) ? gh * Wg2[r * 32 + tid] : 0.f;
            #pragma unroll
            for (int off = 1; off < 64; off <<= 1) part += __shfl_xor(part, off);
            gl[r] = part + bg2[r];
        }
        if (count < 1)  gl[0] = -INFINITY;
        if (count < 17) gl[1] = -INFINITY;
        if (count < 33) gl[2] = -INFINITY;
        float w0 = 0.f, w1 = 0.f, w2 = 0.f;
        if (count > 0) {
            const float mx = fmaxf(gl[0], fmaxf(gl[1], gl[2]));
            const float e0 = expf(gl[0] - mx), e1 = expf(gl[1] - mx), e2 = expf(gl[2] - mx);
            const float es = e0 + e1 + e2;
            w0 = e0 / es; w1 = e1 / es; w2 = e2 / es;
        }
        if (tid == 0) {
            wring[0] = w0; wring[1] = w1; wring[2] = w2;
            nonb[p] = (count == 0) ? (unsigned char)1 : (unsigned char)0;
        }
    }
    // hidden: 48x128, relu(Wpe1 @ rel + bpe1)
    for (int v = tid; v < KK * 128; v += 256) {
        const int s = v >> 7, jj = v & 127;
        const float4 r4 = *(const float4*)(&rel[s][0]);
        const float4 w4 = *(const float4*)(Wpe1 + (size_t)jj * 4);
        float hdd = bpe1[jj] + r4.x * w4.x + r4.y * w4.y + r4.z * w4.z + r4.w * w4.w;
        hid[s][jj] = fmaxf(hdd, 0.f);
    }
    __syncthreads();

    // phase 3: logits + per-ring softmax (wave r owns ring r)
    if (tid < 192) {
        const int s_ = tid >> 2, h_ = tid & 3;
        float acc = 0.f;
        const float4* hp = (const float4*)(&hid[s_][0]);
        const float4* qp = (const float4*)(&qw[h_][0]);
        #pragma unroll
        for (int j4 = 0; j4 < 32; ++j4) {
            float4 hv = hp[j4], qv = qp[j4];
            acc = fmaf(qv.x, hv.x, fmaf(qv.y, hv.y, fmaf(qv.z, hv.z, fmaf(qv.w, hv.w, acc))));
        }
        const float* kr = Kp + ((size_t)b * NPTS + sidx[s_]) * 256 + h_ * 64;
        const float4* qsp = (const float4*)(&qs[h_][0]);
        #pragma unroll
        for (int d4 = 0; d4 < 16; ++d4) {
            float4 kv = *(const float4*)(kr + d4 * 4);
            float4 qv = qsp[d4];
            acc = fmaf(qv.x, kv.x, fmaf(qv.y, kv.y, fmaf(qv.z, kv.z, fmaf(qv.w, kv.w, acc))));
        }
        float logit = svalid[s_] ? acc : -1e9f;
        float mx = logit;
        #pragma unroll
        for (int off = 4; off < 64; off <<= 1) mx = fmaxf(mx, __shfl_xor(mx, off));
        const float e = expf(logit - mx);
        float es = e;
        #pragma unroll
        for (int off = 4; off < 64; off <<= 1) es += __shfl_xor(es, off);
        wsh[s_][h_] = (e / es) * wring[tid >> 6];
    }
    __syncthreads();

    // phase 4: vbar -> vh[p][0:256]  (4 independent gather chains for ILP)
    {
        const int h = tid >> 6, dp = tid & 63;
        const size_t bb = (size_t)b * NPTS;
        const float* vpb = Vp + h * 64 + dp;
        float a0 = 0.f, a1 = 0.f, a2 = 0.f, a3 = 0.f;
        #pragma unroll
        for (int s = 0; s < 12; ++s) {
            a0 = fmaf(wsh[s     ][h], vpb[(bb + sidx[s     ]) * 256], a0);
            a1 = fmaf(wsh[s + 12][h], vpb[(bb + sidx[s + 12]) * 256], a1);
            a2 = fmaf(wsh[s + 24][h], vpb[(bb + sidx[s + 24]) * 256], a2);
            a3 = fmaf(wsh[s + 36][h], vpb[(bb + sidx[s + 36]) * 256], a3);
        }
        vh[(size_t)p * 768 + tid] = (a0 + a1) + (a2 + a3);
    }
    // phase 5: hbar -> vh[p][256:768]  (2 chains)
    for (int v = tid; v < 512; v += 256) {
        const int h = v >> 7, jj = v & 127;
        float a0 = 0.f, a1 = 0.f;
        #pragma unroll
        for (int s = 0; s < 24; ++s) {
            a0 = fmaf(wsh[s     ][h], hid[s     ][jj], a0);
            a1 = fmaf(wsh[s + 24][h], hid[s + 24][jj], a1);
        }
        vh[(size_t)p * 768 + 256 + v] = a0 + a1;
    }
}

// ---------------------------------------------------------------------------
// E3b: LayerNorm epilogue: x = xo + (nonb?0:bout) + feat; LN; out.
__global__ __launch_bounds__(256) void ln_kernel(
    const float* __restrict__ xo, const float* __restrict__ feat,
    const float* __restrict__ bout, const unsigned char* __restrict__ nonb,
    const float* __restrict__ gamma, const float* __restrict__ beta,
    float* __restrict__ out)
{
    const int lane = threadIdx.x & 63;
    const int p = blockIdx.x * 4 + (threadIdx.x >> 6);
    const float4 xv = *(const float4*)&xo  [(size_t)p * 256 + lane * 4];
    const float4 fv = *(const float4*)&feat[(size_t)p * 256 + lane * 4];
    const float4 bv = *(const float4*)&bout[lane * 4];
    const float bm = nonb[p] ? 0.f : 1.f;
    float x0 = xv.x + fv.x + bm * bv.x;
    float x1 = xv.y + fv.y + bm * bv.y;
    float x2 = xv.z + fv.z + bm * bv.z;
    float x3 = xv.w + fv.w + bm * bv.w;
    float s1 = x0 + x1 + x2 + x3;
    float s2 = fmaf(x0, x0, fmaf(x1, x1, fmaf(x2, x2, x3 * x3)));
    #pragma unroll
    for (int off = 1; off < 64; off <<= 1) {
        s1 += __shfl_xor(s1, off);
        s2 += __shfl_xor(s2, off);
    }
    const float mu = s1 * (1.f / 256.f);
    const float var = s2 * (1.f / 256.f) - mu * mu;
    const float rs = 1.f / sqrtf(var + 1e-5f);
    const float4 gv = *(const float4*)&gamma[lane * 4];
    const float4 tv = *(const float4*)&beta [lane * 4];
    float4 o;
    o.x = (x0 - mu) * rs * gv.x + tv.x;
    o.y = (x1 - mu) * rs * gv.y + tv.y;
    o.z = (x2 - mu) * rs * gv.z + tv.z;
    o.w = (x3 - mu) * rs * gv.w + tv.w;
    *(float4*)&out[(size_t)p * 256 + lane * 4] = o;
}

// ---------------------------------------------------------------------------
extern "C" void kernel_launch(void* const* d_in, const int* in_sizes, int n_in,
                              void* d_out, int out_size, void* d_ws, size_t ws_size,
                              hipStream_t stream) {
    (void)in_sizes; (void)n_in; (void)out_size; (void)ws_size;
    const float* features = (const float*)d_in[0];
    const float* coords   = (const float*)d_in[1];
    const float* Wfeat    = (const float*)d_in[2];
    const float* bfeat    = (const float*)d_in[3];
    const float* Wpe1     = (const float*)d_in[4];
    const float* bpe1     = (const float*)d_in[5];
    const float* Wpe2     = (const float*)d_in[6];
    const float* bpe2     = (const float*)d_in[7];
    const float* Win      = (const float*)d_in[8];
    const float* bin_     = (const float*)d_in[9];
    const float* Wout     = (const float*)d_in[10];
    const float* bout     = (const float*)d_in[11];
    const float* Wg1      = (const float*)d_in[12];
    const float* bg1      = (const float*)d_in[13];
    const float* Wg2      = (const float*)d_in[14];
    const float* bg2      = (const float*)d_in[15];
    const float* gamma    = (const float*)d_in[16];
    const float* beta     = (const float*)d_in[17];
    float* out = (float*)d_out;

    // workspace layout (floats); ~76 MB (xo aliases Qm — dead after attn)
    float* ws   = (float*)d_ws;
    float* feat = ws;
    float* Qm   = feat + (size_t)NB * DM;
    float* Kp   = Qm   + (size_t)NB * DM;
    float* Vp   = Kp   + (size_t)NB * DM;
    float* qWa  = Vp   + (size_t)NB * DM;
    float* vh   = qWa  + (size_t)NB * 512;
    float* Wk2  = vh   + (size_t)NB * 768;
    float* Wv2  = Wk2  + 256 * 128;
    float* Wcat = Wv2  + 256 * 128;
    float* WqW2 = Wcat + 256 * 768;
    float* bkf  = WqW2 + 512 * 256;
    float* bvf  = bkf + 256;
    float* bqW2 = bvf + 256;
    float* ndist = bqW2 + 512;
    int*   nidx = (int*)(ndist + (size_t)NB * KK);
    unsigned char* nonb = (unsigned char*)(nidx + (size_t)NB * KK);
    float* xo   = Qm;   // alias: Qm dead after attn_kernel

    prep_wkv2<<<256, 128, 0, stream>>>(Win, Wpe2, bpe2, bin_, Wk2, Wv2, bkf, bvf);
    prep_wqw2<<<512, 256, 0, stream>>>(Win, Wk2, bin_, WqW2, bqW2);
    prep_wcat<<<256, 256, 0, stream>>>(Wout, Wv2, Wcat);

    // feat = features @ Wfeat^T + bfeat
    gemm_plain<<<(NB / 64) * 4, 256, 0, stream>>>(
        features, 256, Wfeat, bfeat, 1.0f, feat, 256, 256, 4);

    // fused Q/K/V/qW
    gemm_qkvw<<<(NB / 64) * 20, 256, 0, stream>>>(
        feat, Win, WqW2, bin_, bkf, bvf, bqW2, Qm, Kp, Vp, qWa);

    knn_kernel<<<NB / 4, 256, 0, stream>>>(coords, nidx, ndist);

    attn_kernel<<<NB, 256, 0, stream>>>(coords, Qm, Kp, Vp, qWa, nidx, ndist,
                                        Wpe1, bpe1, Wg1, bg1, Wg2, bg2, vh, nonb);

    // xo = vh @ Wcat^T   (bias/residual/LN handled by ln_kernel)
    gemm_plain<<<(NB / 64) * 4, 256, 0, stream>>>(
        vh, 768, Wcat, nullptr, 1.0f, xo, 256, 768, 4);

    ln_kernel<<<NB / 4, 256, 0, stream>>>(xo, feat, bout, nonb, gamma, beta, out);
}